// Round 1
// baseline (232.358 us; speedup 1.0000x reference)
//
#include <hip/hip_runtime.h>

#define NN 2048
#define KTOP 256
#define INV_EPS 1000.0f

// ---------------------------------------------------------------------------
// Sort each batch row descending (bitonic, in LDS). One block per batch.
// ---------------------------------------------------------------------------
__global__ __launch_bounds__(256) void sort_desc_k(const float* __restrict__ s,
                                                   float* __restrict__ t) {
    __shared__ float buf[NN];
    const int b = blockIdx.x;
    for (int k = threadIdx.x; k < NN; k += 256) buf[k] = s[b * NN + k];
    __syncthreads();
    for (int k = 2; k <= NN; k <<= 1) {
        for (int j = k >> 1; j > 0; j >>= 1) {
            for (int e = threadIdx.x; e < NN; e += 256) {
                int p = e ^ j;
                if (p > e) {
                    float a = buf[e], c = buf[p];
                    bool desc = ((e & k) == 0);
                    bool sw = desc ? (a < c) : (a > c);
                    if (sw) { buf[e] = c; buf[p] = a; }
                }
            }
            __syncthreads();
        }
    }
    for (int k = threadIdx.x; k < NN; k += 256) t[b * NN + k] = buf[k];
}

// ---------------------------------------------------------------------------
// Pass B: c[b][j] = log( sum_i exp(-(s_i - t_j)^2 / eps) )
// max term is exactly exp(0)=1 (t is a permutation of s) -> naive sum stable.
// One thread per j; s staged in LDS (broadcast reads).
// ---------------------------------------------------------------------------
__global__ __launch_bounds__(256) void passB_k(const float* __restrict__ s,
                                               const float* __restrict__ t,
                                               float* __restrict__ c) {
    __shared__ float ls[NN];
    const int b = blockIdx.x >> 3;            // NN/256 == 8 chunks per batch
    const int j = ((blockIdx.x & 7) << 8) + threadIdx.x;
    for (int k = threadIdx.x; k < NN; k += 256) ls[k] = s[b * NN + k];
    __syncthreads();
    const float tj = t[b * NN + j];
    float a0 = 0.f, a1 = 0.f, a2 = 0.f, a3 = 0.f;
#pragma unroll 4
    for (int i = 0; i < NN; i += 4) {
        float d0 = ls[i + 0] - tj; a0 += __expf(-INV_EPS * d0 * d0);
        float d1 = ls[i + 1] - tj; a1 += __expf(-INV_EPS * d1 * d1);
        float d2 = ls[i + 2] - tj; a2 += __expf(-INV_EPS * d2 * d2);
        float d3 = ls[i + 3] - tj; a3 += __expf(-INV_EPS * d3 * d3);
    }
    c[b * NN + j] = __logf((a0 + a1) + (a2 + a3));
}

// ---------------------------------------------------------------------------
// Pass C: r[b][i] = log( sum_j exp(-(s_i - t_j)^2/eps - c_j) )
// c_j in [0, log(2048)] -> terms bounded, matching-j term >= e^-7.7 -> stable.
// ---------------------------------------------------------------------------
__global__ __launch_bounds__(256) void passC_k(const float* __restrict__ s,
                                               const float* __restrict__ t,
                                               const float* __restrict__ c,
                                               float* __restrict__ r) {
    __shared__ float lt[NN];
    __shared__ float lc[NN];
    const int b = blockIdx.x >> 3;
    const int i = ((blockIdx.x & 7) << 8) + threadIdx.x;
    for (int k = threadIdx.x; k < NN; k += 256) {
        lt[k] = t[b * NN + k];
        lc[k] = c[b * NN + k];
    }
    __syncthreads();
    const float si = s[b * NN + i];
    float a0 = 0.f, a1 = 0.f, a2 = 0.f, a3 = 0.f;
#pragma unroll 4
    for (int j = 0; j < NN; j += 4) {
        { float d = si - lt[j + 0]; a0 += __expf(fmaf(-INV_EPS * d, d, -lc[j + 0])); }
        { float d = si - lt[j + 1]; a1 += __expf(fmaf(-INV_EPS * d, d, -lc[j + 1])); }
        { float d = si - lt[j + 2]; a2 += __expf(fmaf(-INV_EPS * d, d, -lc[j + 2])); }
        { float d = si - lt[j + 3]; a3 += __expf(fmaf(-INV_EPS * d, d, -lc[j + 3])); }
    }
    r[b * NN + i] = __logf((a0 + a1) + (a2 + a3));
}

// ---------------------------------------------------------------------------
// Pass D: cc[b][j] = log( sum_i exp(-(s_i - t_j)^2/eps - r_i) )  == c_j + c2_j
// |r_i| <= log(2048) -> terms in [e^-7.7, 2048*e^7.7] -> stable naive sum.
// ---------------------------------------------------------------------------
__global__ __launch_bounds__(256) void passD_k(const float* __restrict__ s,
                                               const float* __restrict__ t,
                                               const float* __restrict__ r,
                                               float* __restrict__ cc) {
    __shared__ float ls[NN];
    __shared__ float lr[NN];
    const int b = blockIdx.x >> 3;
    const int j = ((blockIdx.x & 7) << 8) + threadIdx.x;
    for (int k = threadIdx.x; k < NN; k += 256) {
        ls[k] = s[b * NN + k];
        lr[k] = r[b * NN + k];
    }
    __syncthreads();
    const float tj = t[b * NN + j];
    float a0 = 0.f, a1 = 0.f, a2 = 0.f, a3 = 0.f;
#pragma unroll 4
    for (int i = 0; i < NN; i += 4) {
        { float d = ls[i + 0] - tj; a0 += __expf(fmaf(-INV_EPS * d, d, -lr[i + 0])); }
        { float d = ls[i + 1] - tj; a1 += __expf(fmaf(-INV_EPS * d, d, -lr[i + 1])); }
        { float d = ls[i + 2] - tj; a2 += __expf(fmaf(-INV_EPS * d, d, -lr[i + 2])); }
        { float d = ls[i + 3] - tj; a3 += __expf(fmaf(-INV_EPS * d, d, -lr[i + 3])); }
    }
    cc[b * NN + j] = __logf((a0 + a1) + (a2 + a3));
}

// ---------------------------------------------------------------------------
// Pass E: out[b][i] = LSE_{j<K}(g) - LSE_j(g),  g = -(s_i - t_j)^2/eps - cc_j
// The second-row-normalization potential r2 cancels algebraically.
// The top-K LSE needs explicit max tracking (its max can be ~-2e4);
// the full-row LSE contains the matching-j term (g >= -cc_j >= -15.3) so
// a naive sum is stable there.
// ---------------------------------------------------------------------------
__global__ __launch_bounds__(256) void passE_k(const float* __restrict__ s,
                                               const float* __restrict__ t,
                                               const float* __restrict__ cc,
                                               float* __restrict__ out) {
    __shared__ float lt[NN];
    __shared__ float lcc[NN];
    const int b = blockIdx.x >> 3;
    const int i = ((blockIdx.x & 7) << 8) + threadIdx.x;
    for (int k = threadIdx.x; k < NN; k += 256) {
        lt[k] = t[b * NN + k];
        lcc[k] = cc[b * NN + k];
    }
    __syncthreads();
    const float si = s[b * NN + i];

    // top-K max
    float m = -3.4e38f;
#pragma unroll 8
    for (int j = 0; j < KTOP; ++j) {
        float d = si - lt[j];
        float g = fmaf(-INV_EPS * d, d, -lcc[j]);
        m = fmaxf(m, g);
    }
    // top-K sum (max-subtracted)
    float part = 0.f;
#pragma unroll 8
    for (int j = 0; j < KTOP; ++j) {
        float d = si - lt[j];
        float g = fmaf(-INV_EPS * d, d, -lcc[j]);
        part += __expf(g - m);
    }
    // full-row sum (naive, stable)
    float a0 = 0.f, a1 = 0.f, a2 = 0.f, a3 = 0.f;
#pragma unroll 4
    for (int j = 0; j < NN; j += 4) {
        { float d = si - lt[j + 0]; a0 += __expf(fmaf(-INV_EPS * d, d, -lcc[j + 0])); }
        { float d = si - lt[j + 1]; a1 += __expf(fmaf(-INV_EPS * d, d, -lcc[j + 1])); }
        { float d = si - lt[j + 2]; a2 += __expf(fmaf(-INV_EPS * d, d, -lcc[j + 2])); }
        { float d = si - lt[j + 3]; a3 += __expf(fmaf(-INV_EPS * d, d, -lcc[j + 3])); }
    }
    float tot = (a0 + a1) + (a2 + a3);

    out[b * NN + i] = m + __logf(part) - __logf(tot);
}

extern "C" void kernel_launch(void* const* d_in, const int* in_sizes, int n_in,
                              void* d_out, int out_size, void* d_ws, size_t ws_size,
                              hipStream_t stream) {
    const float* s = (const float*)d_in[0];
    float* out = (float*)d_out;
    const int total = in_sizes[0];
    const int Bn = total / NN;            // 32 batches

    float* ws = (float*)d_ws;
    float* t  = ws;                       // [Bn][NN] sorted descending
    float* c  = ws + (size_t)Bn * NN;     // col potential 1
    float* r  = ws + 2 * (size_t)Bn * NN; // row potential 1
    float* cc = ws + 3 * (size_t)Bn * NN; // c + c2 (col potentials combined)

    const int blocks = Bn * (NN / 256);   // 256 blocks

    sort_desc_k<<<Bn, 256, 0, stream>>>(s, t);
    passB_k<<<blocks, 256, 0, stream>>>(s, t, c);
    passC_k<<<blocks, 256, 0, stream>>>(s, t, c, r);
    passD_k<<<blocks, 256, 0, stream>>>(s, t, r, cc);
    passE_k<<<blocks, 256, 0, stream>>>(s, t, cc, out);
}

// Round 2
// 86.306 us; speedup vs baseline: 2.6923x; 2.6923x over previous
//
#include <hip/hip_runtime.h>

#define NN 2048
#define KTOP 256
#define INV_EPS 1000.0f
#define WIN 0.33f   // 1000*WIN^2 = 108.9 > 88 + 15.3 (max potential magnitude)

// ---------------------------------------------------------------------------
// Rank-based sort: rank_i = #{k: s_k > s_i} + #{k<i: s_k == s_i}; scatter.
// 8 lanes cooperate per element; 2048 blocks -> full occupancy, no barriers
// beyond the one staging sync.
// ---------------------------------------------------------------------------
__global__ __launch_bounds__(256) void rank_sort_k(const float* __restrict__ s,
                                                   float* __restrict__ t) {
    __shared__ float ls[NN];
    const int b = blockIdx.x >> 6;                 // 64 blocks per batch
    const int obase = (blockIdx.x & 63) << 5;      // 32 elements per block
    for (int k = threadIdx.x; k < NN; k += 256) ls[k] = s[b * NN + k];
    __syncthreads();
    const int o = obase + (threadIdx.x >> 3);
    const int ch = threadIdx.x & 7;
    const float x = ls[o];
    int cnt = 0;
    for (int k = ch; k < NN; k += 8) {
        float v = ls[k];
        cnt += (v > x) || (v == x && k < o);
    }
    cnt += __shfl_xor(cnt, 1);
    cnt += __shfl_xor(cnt, 2);
    cnt += __shfl_xor(cnt, 4);
    if (ch == 0) t[b * NN + cnt] = x;
}

// ---------------------------------------------------------------------------
// Potential pass (covers B, C, D): out[o] = log sum_j exp(-1000*(t_o-t_j)^2
// - aux_j), computed entirely in sorted index space (sums over the batch are
// permutation-invariant). Windowed: terms with |d| > WIN underflow vs the
// matching-element term (>= e^-15.3). 8 lanes per output.
// ---------------------------------------------------------------------------
template <bool HAS_AUX>
__global__ __launch_bounds__(256) void pot_k(const float* __restrict__ t,
                                             const float* __restrict__ aux,
                                             float* __restrict__ out) {
    __shared__ float lt[NN];
    __shared__ float la[HAS_AUX ? NN : 1];
    const int b = blockIdx.x >> 6;
    const int obase = (blockIdx.x & 63) << 5;
    for (int k = threadIdx.x; k < NN; k += 256) {
        lt[k] = t[b * NN + k];
        if (HAS_AUX) la[k] = aux[b * NN + k];
    }
    __syncthreads();
    const int o = obase + (threadIdx.x >> 3);
    const int ch = threadIdx.x & 7;
    const float x = lt[o];

    // window [lo, hi): t descending; lo = first j with t_j < x+WIN,
    // hi = first j with t_j <= x-WIN.
    int lo, hi;
    {
        int l = 0, r = NN;
        while (l < r) { int m = (l + r) >> 1; if (lt[m] < x + WIN) r = m; else l = m + 1; }
        lo = l;
    }
    {
        int l = 0, r = NN;
        while (l < r) { int m = (l + r) >> 1; if (lt[m] <= x - WIN) r = m; else l = m + 1; }
        hi = l;
    }

    float acc = 0.f;
    for (int j = lo + ch; j < hi; j += 8) {
        float d = x - lt[j];
        float e = -INV_EPS * d * d;
        if (HAS_AUX) e -= la[j];
        acc += __expf(e);
    }
    acc += __shfl_xor(acc, 1);
    acc += __shfl_xor(acc, 2);
    acc += __shfl_xor(acc, 4);
    if (ch == 0) out[b * NN + o] = __logf(acc);
}

// ---------------------------------------------------------------------------
// Final pass: out[i] = LSE_{j<K}(g) - LSE_j(g), g = -1000*(s_i - t_j)^2 - cc_j.
// Top-K part needs explicit max tracking (max can be ~-2e4) -> exact 256-term
// loop, max-subtracted. Full-row LSE contains the matching term (>= e^-15.3)
// -> windowed naive sum. Output in ORIGINAL index order.
// ---------------------------------------------------------------------------
__global__ __launch_bounds__(256) void topk_k(const float* __restrict__ s,
                                              const float* __restrict__ t,
                                              const float* __restrict__ cc,
                                              float* __restrict__ out) {
    __shared__ float lt[NN];
    __shared__ float lc[NN];
    const int b = blockIdx.x >> 6;
    const int obase = (blockIdx.x & 63) << 5;
    for (int k = threadIdx.x; k < NN; k += 256) {
        lt[k] = t[b * NN + k];
        lc[k] = cc[b * NN + k];
    }
    __syncthreads();
    const int o = obase + (threadIdx.x >> 3);
    const int ch = threadIdx.x & 7;
    const float x = s[b * NN + o];

    // top-K max (exact, 32 iters/lane)
    float m = -3.4e38f;
    for (int j = ch; j < KTOP; j += 8) {
        float d = x - lt[j];
        m = fmaxf(m, fmaf(-INV_EPS * d, d, -lc[j]));
    }
    m = fmaxf(m, __shfl_xor(m, 1));
    m = fmaxf(m, __shfl_xor(m, 2));
    m = fmaxf(m, __shfl_xor(m, 4));

    // top-K sum, max-subtracted
    float part = 0.f;
    for (int j = ch; j < KTOP; j += 8) {
        float d = x - lt[j];
        part += __expf(fmaf(-INV_EPS * d, d, -lc[j]) - m);
    }
    part += __shfl_xor(part, 1);
    part += __shfl_xor(part, 2);
    part += __shfl_xor(part, 4);

    // full-row windowed sum
    int lo, hi;
    {
        int l = 0, r = NN;
        while (l < r) { int mm = (l + r) >> 1; if (lt[mm] < x + WIN) r = mm; else l = mm + 1; }
        lo = l;
    }
    {
        int l = 0, r = NN;
        while (l < r) { int mm = (l + r) >> 1; if (lt[mm] <= x - WIN) r = mm; else l = mm + 1; }
        hi = l;
    }
    float acc = 0.f;
    for (int j = lo + ch; j < hi; j += 8) {
        float d = x - lt[j];
        acc += __expf(fmaf(-INV_EPS * d, d, -lc[j]));
    }
    acc += __shfl_xor(acc, 1);
    acc += __shfl_xor(acc, 2);
    acc += __shfl_xor(acc, 4);

    if (ch == 0) out[b * NN + o] = m + __logf(part) - __logf(acc);
}

extern "C" void kernel_launch(void* const* d_in, const int* in_sizes, int n_in,
                              void* d_out, int out_size, void* d_ws, size_t ws_size,
                              hipStream_t stream) {
    const float* s = (const float*)d_in[0];
    float* out = (float*)d_out;
    const int total = in_sizes[0];
    const int Bn = total / NN;            // 32 batches

    float* ws = (float*)d_ws;
    float* t  = ws;                        // [Bn][NN] sorted descending
    float* c  = ws + (size_t)Bn * NN;      // col potential 1 (sorted space)
    float* r  = ws + 2 * (size_t)Bn * NN;  // row potential 1 (sorted space)
    float* cc = ws + 3 * (size_t)Bn * NN;  // col potentials combined (sorted)

    const int blocks = Bn * 64;            // 2048 blocks, 8 lanes/output

    rank_sort_k<<<blocks, 256, 0, stream>>>(s, t);
    pot_k<false><<<blocks, 256, 0, stream>>>(t, nullptr, c);
    pot_k<true><<<blocks, 256, 0, stream>>>(t, c, r);
    pot_k<true><<<blocks, 256, 0, stream>>>(t, r, cc);
    topk_k<<<blocks, 256, 0, stream>>>(s, t, cc, out);
}